// Round 5
// baseline (367.767 us; speedup 1.0000x reference)
//
#include <hip/hip_runtime.h>
#include <hip/hip_bf16.h>
#include <math.h>

// Problem: B=8, N=1024, D=1024, H=16, DH=64.  M_TOK = B*N = 8192.
#define BB 8
#define NN 1024
#define DD 1024
#define HH 16
#define DH 64
#define MTOK 8192

typedef __attribute__((ext_vector_type(8))) short short8;   // 8 bf16 (4 VGPRs) MFMA frag
typedef __attribute__((ext_vector_type(4))) short short4v;
typedef __attribute__((ext_vector_type(4))) float float4v;  // MFMA C/D frag

#define SCL_Q 0.18033688011112042f   // log2(e)/8 folded into Q projection

__device__ __forceinline__ ushort f2bf(float f) {
    union { float f; unsigned u; } v; v.f = f;
    unsigned r = v.u + 0x7fffu + ((v.u >> 16) & 1u);   // RNE
    return (ushort)(r >> 16);
}

// packed f32x2 -> bf16x2 (round-half-up) in one v_perm_b32 + two v_add:
// result = [hi16(b+0x8000) | hi16(a+0x8000)]  (a -> element 0)
__device__ __forceinline__ unsigned pkbf2(float a, float b) {
    union { float f; unsigned u; } x, y; x.f = a; y.f = b;
    return __builtin_amdgcn_perm(y.u + 0x8000u, x.u + 0x8000u, 0x07060302u);
}

// async global->LDS, 16B per lane. LDS dest is wave-uniform base + lane*16.
__device__ __forceinline__ void gl_lds16(const ushort* g, ushort* l) {
    __builtin_amdgcn_global_load_lds(
        (const __attribute__((address_space(1))) void*)g,
        (__attribute__((address_space(3))) void*)l, 16, 0, 0);
}

// f32 staging: load 8 f32, perm-pack to 8 bf16, one b128 LDS write
__device__ __forceinline__ void stage8f_sw(const float* __restrict__ p, ushort* d) {
    float4v a = *(const float4v*)p;
    float4v b = *(const float4v*)(p + 4);
    uint4 w;
    w.x = pkbf2(a[0], a[1]); w.y = pkbf2(a[2], a[3]);
    w.z = pkbf2(b[0], b[1]); w.w = pkbf2(b[2], b[3]);
    *(uint4*)d = w;
}

// =====================================================================
// bf16 convert kernel (weights only now): up to 7 tensors, 8 elems/thread
// =====================================================================
struct CvtArgs {
    const float* src[7];
    ushort* dst[7];
    int n[7];
};
__global__ __launch_bounds__(256) void cvt_bf16(CvtArgs a) {
    const int z = blockIdx.y;
    const int idx = (blockIdx.x * 256 + threadIdx.x) * 8;
    if (idx >= a.n[z]) return;
    const float* s = a.src[z];
    float4v x0 = *(const float4v*)(s + idx);
    float4v x1 = *(const float4v*)(s + idx + 4);
    short8 o;
    o[0]=(short)f2bf(x0[0]); o[1]=(short)f2bf(x0[1]); o[2]=(short)f2bf(x0[2]); o[3]=(short)f2bf(x0[3]);
    o[4]=(short)f2bf(x1[0]); o[5]=(short)f2bf(x1[1]); o[6]=(short)f2bf(x1[2]); o[7]=(short)f2bf(x1[3]);
    *(short8*)(a.dst[z] + idx) = o;
}

// =====================================================================
// GEMM core: C[m,n] = (A[m,:] . W[n,:] + bias[n]) * oscale
// Grid: x = m-tile (64), y = n-tile (8)  ->  the 8 blocks sharing an A
// row-panel have linear ids 64 apart => same XCD => A fetched once/XCD.
// Both operands land in XOR-swizzled stride-64 LDS (conflict-free b128):
//   bf16 source: global_load_lds 16B/lane; f32 source: perm-pack staging.
// MODE 0: out bf16 [b,h,n_tok,d]  (C^T order -> b64 packed stores)
// MODE 1: out bf16 [b,h,d,n_tok]  (C order  -> b64 packed stores)
// MODE 2: out f32  [MTOK,1024]    (C^T order -> b128 packed stores)
// Tile 128x128, BK=64, 256 thr (4 waves, each 64x64 = 4x4 MFMA 16x16x32).
// =====================================================================
template <typename TA, typename TW, int MODE>
__device__ __forceinline__ void gemm_core(const void* Ap, const void* Wp,
                                          const float* __restrict__ bias,
                                          void* __restrict__ outp, float oscale,
                                          ushort* As, ushort* Bs) {
    constexpr bool A_BF = (sizeof(TA) == 2);
    constexpr bool W_BF = (sizeof(TW) == 2);

    const int tid  = threadIdx.x;
    const int wid  = tid >> 6;
    const int lane = tid & 63;
    const int quad = lane >> 4;
    const int l15  = lane & 15;
    const int wr   = wid >> 1;
    const int wc   = wid & 1;
    const int m0   = blockIdx.x * 128;   // m on x: A-sharing blocks same XCD
    const int n0   = blockIdx.y * 128;
    const int sw   = l15 & 7;

    float4v acc[4][4] = {};

    for (int kt = 0; kt < 16; ++kt) {
        const int k0 = kt * 64;
        if constexpr (A_BF) {
            const ushort* A = (const ushort*)Ap;
            #pragma unroll
            for (int t = 0; t < 4; ++t) {
                int chunk = t * 4 + wid;
                int row   = chunk * 8 + (lane >> 3);
                int kc    = ((lane & 7) ^ (lane >> 3)) * 8;   // XOR swizzle
                gl_lds16(A + (size_t)(m0 + row) * 1024 + k0 + kc, As + chunk * 512);
            }
        } else {
            const float* A = (const float*)Ap;
            #pragma unroll
            for (int i = 0; i < 4; ++i) {
                int cidx = i * 256 + tid;
                int row  = cidx >> 3;
                int cc   = cidx & 7;
                int swc  = cc ^ (row & 7);
                stage8f_sw(A + (size_t)(m0 + row) * 1024 + k0 + cc * 8,
                           &As[row * 64 + swc * 8]);
            }
        }
        if constexpr (W_BF) {
            const ushort* W = (const ushort*)Wp;
            #pragma unroll
            for (int t = 0; t < 4; ++t) {
                int chunk = t * 4 + wid;
                int row   = chunk * 8 + (lane >> 3);
                int kc    = ((lane & 7) ^ (lane >> 3)) * 8;
                gl_lds16(W + (size_t)(n0 + row) * 1024 + k0 + kc, Bs + chunk * 512);
            }
        } else {
            const float* W = (const float*)Wp;
            #pragma unroll
            for (int i = 0; i < 4; ++i) {
                int cidx = i * 256 + tid;
                int row  = cidx >> 3;
                int cc   = cidx & 7;
                int swc  = cc ^ (row & 7);
                stage8f_sw(W + (size_t)(n0 + row) * 1024 + k0 + cc * 8,
                           &Bs[row * 64 + swc * 8]);
            }
        }
        __syncthreads();

        #pragma unroll
        for (int kk = 0; kk < 2; ++kk) {
            short8 af[4], bfr[4];
            #pragma unroll
            for (int i = 0; i < 4; ++i)
                af[i] = *(const short8*)&As[(wr * 64 + i * 16 + l15) * 64 +
                                            ((kk * 4 + quad) ^ sw) * 8];
            #pragma unroll
            for (int j = 0; j < 4; ++j)
                bfr[j] = *(const short8*)&Bs[(wc * 64 + j * 16 + l15) * 64 +
                                             ((kk * 4 + quad) ^ sw) * 8];
            #pragma unroll
            for (int i = 0; i < 4; ++i)
                #pragma unroll
                for (int j = 0; j < 4; ++j) {
                    if constexpr (MODE == 1)
                        acc[i][j] = __builtin_amdgcn_mfma_f32_16x16x32_bf16(af[i], bfr[j], acc[i][j], 0, 0, 0);
                    else   // C^T: feature-major
                        acc[j][i] = __builtin_amdgcn_mfma_f32_16x16x32_bf16(bfr[j], af[i], acc[j][i], 0, 0, 0);
                }
        }
        __syncthreads();
    }

    if constexpr (MODE == 1) {
        // C layout: row = token (quad*4+r), col = feature (l15) -> tokens contiguous in vt
        ushort* out = (ushort*)outp;
        #pragma unroll
        for (int j = 0; j < 4; ++j) {
            const int col = n0 + wc * 64 + j * 16 + l15;
            const float bv = bias[col];
            const int h = col >> 6;
            const int d = col & 63;
            #pragma unroll
            for (int i = 0; i < 4; ++i) {
                const int rowbase = m0 + wr * 64 + i * 16 + quad * 4;
                int bi = rowbase >> 10, n = rowbase & 1023;
                uint2 w;
                w.x = pkbf2(acc[i][j][0] + bv, acc[i][j][1] + bv);
                w.y = pkbf2(acc[i][j][2] + bv, acc[i][j][3] + bv);
                *(uint2*)&out[(((size_t)(bi * HH + h) * DH + d) * NN) + n] = w;
            }
        }
    } else {
        // C^T layout: row = feature (quad*4+r), col = token (l15) -> features contiguous
        #pragma unroll
        for (int p = 0; p < 4; ++p) {
            const int fb = n0 + wc * 64 + p * 16 + quad * 4;
            const float4v bv4 = *(const float4v*)&bias[fb];
            const int h = fb >> 6;
            const int d = fb & 63;
            #pragma unroll
            for (int q = 0; q < 4; ++q) {
                const int tok = m0 + wr * 64 + q * 16 + l15;
                if constexpr (MODE == 0) {
                    ushort* out = (ushort*)outp;
                    int bi = tok >> 10, n = tok & 1023;
                    uint2 w;
                    w.x = pkbf2((acc[p][q][0] + bv4[0]) * oscale,
                                (acc[p][q][1] + bv4[1]) * oscale);
                    w.y = pkbf2((acc[p][q][2] + bv4[2]) * oscale,
                                (acc[p][q][3] + bv4[3]) * oscale);
                    *(uint2*)&out[(((size_t)(bi * HH + h) * NN + n) * DH) + d] = w;
                } else {
                    float* out = (float*)outp;
                    float4v ov;
                    #pragma unroll
                    for (int r = 0; r < 4; ++r) ov[r] = acc[p][q][r] + bv4[r];
                    *(float4v*)&out[(size_t)tok * 1024 + fb] = ov;
                }
            }
        }
    }
}

template <typename TA, typename TW>
__global__ __launch_bounds__(256) void proj3(const void* q, const void* k, const void* r,
                                             const void* Wq, const void* Wk, const void* Wv,
                                             const float* bq, const float* bk, const float* bv,
                                             ushort* qh, ushort* kh, ushort* vt) {
    __shared__ ushort As[128 * 64];
    __shared__ ushort Bs[128 * 64];
    if (blockIdx.z == 0)      gemm_core<TA, TW, 0>(q, Wq, bq, qh, SCL_Q, As, Bs);
    else if (blockIdx.z == 1) gemm_core<TA, TW, 0>(k, Wk, bk, kh, 1.0f, As, Bs);
    else                      gemm_core<TA, TW, 1>(r, Wv, bv, vt, 1.0f, As, Bs);
}

template <typename TA, typename TW>
__global__ __launch_bounds__(256) void gemm_out(const void* A, const void* W,
                                                const float* bias, float* out) {
    __shared__ ushort As[128 * 64];
    __shared__ ushort Bs[128 * 64];
    gemm_core<TA, TW, 2>(A, W, bias, out, 1.0f, As, Bs);
}

// =====================================================================
// Fused flash attention, max-free softmax, transposed dataflow.
// qh is pre-scaled by log2(e)/8 in proj3 -> p = exp2(sacc) directly.
//   S^T = mfma(K, Q)  -> C/D holds (key=quad*4+r, qrow=l15)
//   P^T write: perm-packed b64 -> P[qrow][key] (stride 72)
//   O^T = mfma(V^T, P^T) -> C/D (d=quad*4+r, qrow=l15) -> b64 global stores
// One block = one (b,h) x 128 Q rows; 4 waves x 32 rows (2 sub-tiles u).
// Grid (bh, qt): all qt blocks of a (b,h) land on one XCD.
// =====================================================================
__global__ __launch_bounds__(256) void attn_fused(const ushort* __restrict__ qh,
                                                  const ushort* __restrict__ kh,
                                                  const ushort* __restrict__ vt,
                                                  ushort* __restrict__ o) {
    __shared__ ushort Ks[64 * 64];       // [key][d] swizzled
    __shared__ ushort Vs[64 * 64];       // [d][key] swizzled
    __shared__ ushort Ps[4][2][16 * 72]; // per-(wave,u) P[qrow][key], stride 72

    const int tid  = threadIdx.x;
    const int wid  = tid >> 6;
    const int lane = tid & 63;
    const int quad = lane >> 4;
    const int l15  = lane & 15;
    const int sw   = l15 & 7;
    const int bh   = blockIdx.x;         // b*16 + h
    const int qt   = blockIdx.y;         // 0..7, 128 Q rows each
    const int h    = bh & 15;
    const int b    = bh >> 4;

    const ushort* qb = qh + (size_t)bh * NN * DH;
    const ushort* kb = kh + (size_t)bh * NN * DH;
    const ushort* vb = vt + (size_t)bh * DH * NN;

    // Q fragments: lane holds Q[qrow][k = s*32 + quad*8 + j]
    short8 qf[2][2];
    #pragma unroll
    for (int u = 0; u < 2; ++u) {
        const int qrow = qt * 128 + wid * 32 + u * 16 + l15;
        qf[u][0] = *(const short8*)(qb + (size_t)qrow * DH + quad * 8);
        qf[u][1] = *(const short8*)(qb + (size_t)qrow * DH + 32 + quad * 8);
    }

    float lsum[2] = {0.f, 0.f};
    float4v oaccT[2][4] = {};

    for (int kt = 0; kt < 16; ++kt) {
        // stage K [64 keys][64 d], V^T [64 d][64 keys], XOR-swizzled
        #pragma unroll
        for (int t = 0; t < 2; ++t) {
            int chunk = t * 4 + wid;
            int row   = chunk * 8 + (lane >> 3);
            int kc    = ((lane & 7) ^ (lane >> 3)) * 8;
            gl_lds16(kb + (size_t)(kt * 64 + row) * DH + kc, Ks + chunk * 512);
            gl_lds16(vb + (size_t)row * NN + kt * 64 + kc, Vs + chunk * 512);
        }
        __syncthreads();

        // S^T = K . Q^T  (keys as rows)
        float4v sacc[2][4] = {};
        #pragma unroll
        for (int s = 0; s < 2; ++s)
            #pragma unroll
            for (int c = 0; c < 4; ++c) {
                short8 kf = *(const short8*)&Ks[(c * 16 + l15) * 64 + ((s * 4 + quad) ^ sw) * 8];
                #pragma unroll
                for (int u = 0; u < 2; ++u)
                    sacc[u][c] = __builtin_amdgcn_mfma_f32_16x16x32_bf16(kf, qf[u][s], sacc[u][c], 0, 0, 0);
            }

        // p = exp2(s) (scale pre-folded into Q); packed b64 P-writes
        #pragma unroll
        for (int u = 0; u < 2; ++u)
            #pragma unroll
            for (int c = 0; c < 4; ++c) {
                float p0 = exp2f(sacc[u][c][0]);
                float p1 = exp2f(sacc[u][c][1]);
                float p2 = exp2f(sacc[u][c][2]);
                float p3 = exp2f(sacc[u][c][3]);
                lsum[u] += (p0 + p1) + (p2 + p3);
                uint2 w;
                w.x = pkbf2(p0, p1);
                w.y = pkbf2(p2, p3);
                *(uint2*)&Ps[wid][u][l15 * 72 + c * 16 + quad * 4] = w;
            }

        // O^T += V^T . P^T   (wave-private Ps: waitcnt only, no barrier)
        #pragma unroll
        for (int s = 0; s < 2; ++s) {
            short8 pf[2];
            #pragma unroll
            for (int u = 0; u < 2; ++u)
                pf[u] = *(const short8*)&Ps[wid][u][l15 * 72 + s * 32 + quad * 8];
            #pragma unroll
            for (int nn = 0; nn < 4; ++nn) {
                short8 vf = *(const short8*)&Vs[(nn * 16 + l15) * 64 + ((s * 4 + quad) ^ sw) * 8];
                #pragma unroll
                for (int u = 0; u < 2; ++u)
                    oaccT[u][nn] = __builtin_amdgcn_mfma_f32_16x16x32_bf16(vf, pf[u], oaccT[u][nn], 0, 0, 0);
            }
        }
        __syncthreads();   // before restaging Ks/Vs
    }

    // epilogue: lane's qrow = l15; reduce denominator over the 4 quads
    #pragma unroll
    for (int u = 0; u < 2; ++u) {
        float t = lsum[u];
        t += __shfl_xor(t, 16);
        t += __shfl_xor(t, 32);
        float inv = 1.0f / t;
        int row = qt * 128 + wid * 32 + u * 16 + l15;
        size_t base = ((size_t)b * NN + row) * DD + h * 64 + quad * 4;
        #pragma unroll
        for (int nn = 0; nn < 4; ++nn) {
            uint2 w;
            w.x = pkbf2(oaccT[u][nn][0] * inv, oaccT[u][nn][1] * inv);
            w.y = pkbf2(oaccT[u][nn][2] * inv, oaccT[u][nn][3] * inv);
            *(uint2*)&o[base + nn * 16] = w;
        }
    }
}

// =====================================================================
// Fused epilogue: res = LN(mha + q; g1,b1); out = LN(relu(res)+res; g2,b2)
// =====================================================================
__global__ __launch_bounds__(256) void ln_fuse(const float* __restrict__ mha,
                                               const float* __restrict__ q,
                                               const float* __restrict__ g1,
                                               const float* __restrict__ b1,
                                               const float* __restrict__ g2,
                                               const float* __restrict__ b2,
                                               float* __restrict__ out) {
    __shared__ float red1[8];
    __shared__ float red2[8];
    const int tid  = threadIdx.x;
    const int wid  = tid >> 6;
    const int lane = tid & 63;
    const size_t base = (size_t)blockIdx.x * 1024 + tid * 4;

    float4v xv = *(const float4v*)(mha + base);
    float4v qv = *(const float4v*)(q + base);
    float x[4];
    float s = 0.f, ss = 0.f;
    for (int i = 0; i < 4; ++i) {
        x[i] = xv[i] + qv[i];
        s += x[i]; ss += x[i] * x[i];
    }
    for (int off = 1; off < 64; off <<= 1) {
        s += __shfl_xor(s, off); ss += __shfl_xor(ss, off);
    }
    if (lane == 0) { red1[wid * 2] = s; red1[wid * 2 + 1] = ss; }
    __syncthreads();
    s  = red1[0] + red1[2] + red1[4] + red1[6];
    ss = red1[1] + red1[3] + red1[5] + red1[7];
    float mu = s * (1.0f / 1024.0f);
    float rstd = rsqrtf(ss * (1.0f / 1024.0f) - mu * mu + 1e-5f);

    float4v g1v = *(const float4v*)(g1 + tid * 4);
    float4v b1v = *(const float4v*)(b1 + tid * 4);
    float y[4];
    float s2 = 0.f, ss2 = 0.f;
    for (int i = 0; i < 4; ++i) {
        float rr = (x[i] - mu) * rstd * g1v[i] + b1v[i];
        y[i] = fmaxf(rr, 0.f) + rr;
        s2 += y[i]; ss2 += y[i] * y[i];
    }
    for (int off = 1; off < 64; off <<= 1) {
        s2 += __shfl_xor(s2, off); ss2 += __shfl_xor(ss2, off);
    }
    if (lane == 0) { red2[wid * 2] = s2; red2[wid * 2 + 1] = ss2; }
    __syncthreads();
    s2  = red2[0] + red2[2] + red2[4] + red2[6];
    ss2 = red2[1] + red2[3] + red2[5] + red2[7];
    float mu2 = s2 * (1.0f / 1024.0f);
    float rstd2 = rsqrtf(ss2 * (1.0f / 1024.0f) - mu2 * mu2 + 1e-5f);

    float4v g2v = *(const float4v*)(g2 + tid * 4);
    float4v b2v = *(const float4v*)(b2 + tid * 4);
    float4v ov;
    for (int i = 0; i < 4; ++i) ov[i] = (y[i] - mu2) * rstd2 * g2v[i] + b2v[i];
    *(float4v*)(out + base) = ov;
}

extern "C" void kernel_launch(void* const* d_in, const int* in_sizes, int n_in,
                              void* d_out, int out_size, void* d_ws, size_t ws_size,
                              hipStream_t stream) {
    const float* k  = (const float*)d_in[0];
    const float* q  = (const float*)d_in[1];
    const float* r  = (const float*)d_in[2];
    const float* Wk = (const float*)d_in[3];
    const float* bk = (const float*)d_in[4];
    const float* Wq = (const float*)d_in[5];
    const float* bq = (const float*)d_in[6];
    const float* Wv = (const float*)d_in[7];
    const float* bv = (const float*)d_in[8];
    const float* Wo = (const float*)d_in[9];
    const float* bo = (const float*)d_in[10];
    const float* g1 = (const float*)d_in[11];
    const float* b1 = (const float*)d_in[12];
    const float* g2 = (const float*)d_in[13];
    const float* b2 = (const float*)d_in[14];

    char* ws = (char*)d_ws;
    const size_t MB = 1u << 20;
    dim3 blk(256);

    if (ws_size >= 73 * MB) {
        ushort* qh  = (ushort*)(ws);            // 16 MB [B,H,N,DH] (scaled by SCL_Q)
        ushort* kh  = (ushort*)(ws + 16 * MB);  // 16 MB
        ushort* vt  = (ushort*)(ws + 32 * MB);  // 16 MB [B,H,DH,N]
        ushort* ob  = (ushort*)(ws + 48 * MB);  // 16 MB [B,N,D]
        ushort* Wqc = (ushort*)(ws + 64 * MB);  // 2 MB each
        ushort* Wkc = (ushort*)(ws + 66 * MB);
        ushort* Wvc = (ushort*)(ws + 68 * MB);
        ushort* Woc = (ushort*)(ws + 70 * MB);
        float*  mh  = (float*)(ws);             // 32 MB, reuses qh/kh after attn

        CvtArgs ca;
        ca.src[0] = Wq; ca.dst[0] = Wqc; ca.n[0] = DD * DD;
        ca.src[1] = Wk; ca.dst[1] = Wkc; ca.n[1] = DD * DD;
        ca.src[2] = Wv; ca.dst[2] = Wvc; ca.n[2] = DD * DD;
        ca.src[3] = Wo; ca.dst[3] = Woc; ca.n[3] = DD * DD;
        for (int i = 4; i < 7; ++i) { ca.src[i] = Wq; ca.dst[i] = Wqc; ca.n[i] = 0; }
        cvt_bf16<<<dim3(512, 4), blk, 0, stream>>>(ca);

        proj3<float, ushort><<<dim3(64, 8, 3), blk, 0, stream>>>(
            q, k, r, Wqc, Wkc, Wvc, bq, bk, bv, qh, kh, vt);
        attn_fused<<<dim3(HH * BB, 8), blk, 0, stream>>>(qh, kh, vt, ob);
        gemm_out<ushort, ushort><<<dim3(64, 8), blk, 0, stream>>>(ob, Woc, bo, mh);
        ln_fuse<<<dim3(MTOK), blk, 0, stream>>>(mh, q, g1, b1, g2, b2, (float*)d_out);
    } else {
        // 64 MB fallback: W converts live in the (not-yet-written) ob region;
        // Wo staged f32 in gemm_out.
        ushort* qh  = (ushort*)(ws);
        ushort* kh  = (ushort*)(ws + 16 * MB);
        ushort* vt  = (ushort*)(ws + 32 * MB);
        ushort* ob  = (ushort*)(ws + 48 * MB);
        ushort* Wqc = (ushort*)(ws + 48 * MB);  // dead once attn writes ob
        ushort* Wkc = (ushort*)(ws + 50 * MB);
        ushort* Wvc = (ushort*)(ws + 52 * MB);
        float*  mh  = (float*)(ws);             // reuses qh/kh after attn

        CvtArgs ca;
        ca.src[0] = Wq; ca.dst[0] = Wqc; ca.n[0] = DD * DD;
        ca.src[1] = Wk; ca.dst[1] = Wkc; ca.n[1] = DD * DD;
        ca.src[2] = Wv; ca.dst[2] = Wvc; ca.n[2] = DD * DD;
        for (int i = 3; i < 7; ++i) { ca.src[i] = Wq; ca.dst[i] = Wqc; ca.n[i] = 0; }
        cvt_bf16<<<dim3(512, 3), blk, 0, stream>>>(ca);

        proj3<float, ushort><<<dim3(64, 8, 3), blk, 0, stream>>>(
            q, k, r, Wqc, Wkc, Wvc, bq, bk, bv, qh, kh, vt);
        attn_fused<<<dim3(HH * BB, 8), blk, 0, stream>>>(qh, kh, vt, ob);
        gemm_out<ushort, float><<<dim3(64, 8), blk, 0, stream>>>(ob, Wo, bo, mh);
        ln_fuse<<<dim3(MTOK), blk, 0, stream>>>(mh, q, g1, b1, g2, b2, (float*)d_out);
    }
}

// Round 6
// 351.554 us; speedup vs baseline: 1.0461x; 1.0461x over previous
//
#include <hip/hip_runtime.h>
#include <hip/hip_bf16.h>
#include <math.h>

// Problem: B=8, N=1024, D=1024, H=16, DH=64.  M_TOK = B*N = 8192.
#define BB 8
#define NN 1024
#define DD 1024
#define HH 16
#define DH 64
#define MTOK 8192

typedef __attribute__((ext_vector_type(8))) short short8;   // 8 bf16 (4 VGPRs) MFMA frag
typedef __attribute__((ext_vector_type(4))) short short4v;
typedef __attribute__((ext_vector_type(4))) float float4v;  // MFMA C/D frag

#define SCL_Q 0.18033688011112042f   // log2(e)/8 folded into Q projection output

__device__ __forceinline__ ushort f2bf(float f) {
    union { float f; unsigned u; } v; v.f = f;
    unsigned r = v.u + 0x7fffu + ((v.u >> 16) & 1u);   // RNE
    return (ushort)(r >> 16);
}

// packed f32x2 -> bf16x2 (round-half-up): two v_add + one v_perm
__device__ __forceinline__ unsigned pkbf2(float a, float b) {
    union { float f; unsigned u; } x, y; x.f = a; y.f = b;
    return __builtin_amdgcn_perm(y.u + 0x8000u, x.u + 0x8000u, 0x07060302u);
}

// async global->LDS, 16B per lane. LDS dest is wave-uniform base + lane*16.
__device__ __forceinline__ void gl_lds16(const ushort* g, ushort* l) {
    __builtin_amdgcn_global_load_lds(
        (const __attribute__((address_space(1))) void*)g,
        (__attribute__((address_space(3))) void*)l, 16, 0, 0);
}

// f32 staging (fallback path only): load 8 f32, perm-pack, one b128 LDS write
__device__ __forceinline__ void stage8f_sw(const float* __restrict__ p, ushort* d) {
    float4v a = *(const float4v*)p;
    float4v b = *(const float4v*)(p + 4);
    uint4 w;
    w.x = pkbf2(a[0], a[1]); w.y = pkbf2(a[2], a[3]);
    w.z = pkbf2(b[0], b[1]); w.w = pkbf2(b[2], b[3]);
    *(uint4*)d = w;
}

// =====================================================================
// bf16 convert kernel: up to 7 tensors, 8 elements/thread, perm-packed
// =====================================================================
struct CvtArgs {
    const float* src[7];
    ushort* dst[7];
    int n[7];
};
__global__ __launch_bounds__(256) void cvt_bf16(CvtArgs a) {
    const int z = blockIdx.y;
    const int idx = (blockIdx.x * 256 + threadIdx.x) * 8;
    if (idx >= a.n[z]) return;
    const float* s = a.src[z];
    float4v x0 = *(const float4v*)(s + idx);
    float4v x1 = *(const float4v*)(s + idx + 4);
    uint4 w;
    w.x = pkbf2(x0[0], x0[1]); w.y = pkbf2(x0[2], x0[3]);
    w.z = pkbf2(x1[0], x1[1]); w.w = pkbf2(x1[2], x1[3]);
    *(uint4*)(a.dst[z] + idx) = w;
}

// =====================================================================
// GEMM core: C[m,n] = (A[m,:] . W[n,:] + bias[n]) * oscale
// Grid: x = m-tile (64), y = n-tile (8)  ->  the 8 blocks sharing an A
// row-panel have linear ids 64 apart => same XCD => A fetched once/XCD.
// bf16 operands: global_load_lds 16B/lane into XOR-swizzled stride-64 LDS
// (conflict-free b128 reads).  f32 operands (fallback): perm-pack staging.
// MODE 0: out bf16 [b,h,n_tok,d]  (C^T order -> b64 packed stores)
// MODE 1: out bf16 [b,h,d,n_tok]  (C order  -> b64 packed stores)
// MODE 2: out f32  [MTOK,1024]    (C^T order -> b128 packed stores)
// Tile 128x128, BK=64, 256 thr (4 waves, each 64x64 = 4x4 MFMA 16x16x32).
// =====================================================================
template <typename TA, typename TW, int MODE>
__device__ __forceinline__ void gemm_core(const void* Ap, const void* Wp,
                                          const float* __restrict__ bias,
                                          void* __restrict__ outp, float oscale,
                                          ushort* As, ushort* Bs) {
    constexpr bool A_BF = (sizeof(TA) == 2);
    constexpr bool W_BF = (sizeof(TW) == 2);

    const int tid  = threadIdx.x;
    const int wid  = tid >> 6;
    const int lane = tid & 63;
    const int quad = lane >> 4;
    const int l15  = lane & 15;
    const int wr   = wid >> 1;
    const int wc   = wid & 1;
    const int m0   = blockIdx.x * 128;   // m on x: A-sharing blocks same XCD
    const int n0   = blockIdx.y * 128;
    const int sw   = l15 & 7;

    float4v acc[4][4] = {};

    for (int kt = 0; kt < 16; ++kt) {
        const int k0 = kt * 64;
        if constexpr (A_BF) {
            const ushort* A = (const ushort*)Ap;
            #pragma unroll
            for (int t = 0; t < 4; ++t) {
                int chunk = t * 4 + wid;
                int row   = chunk * 8 + (lane >> 3);
                int kc    = ((lane & 7) ^ (lane >> 3)) * 8;   // XOR swizzle
                gl_lds16(A + (size_t)(m0 + row) * 1024 + k0 + kc, As + chunk * 512);
            }
        } else {
            const float* A = (const float*)Ap;
            #pragma unroll
            for (int i = 0; i < 4; ++i) {
                int cidx = i * 256 + tid;
                int row  = cidx >> 3;
                int cc   = cidx & 7;
                int swc  = cc ^ (row & 7);
                stage8f_sw(A + (size_t)(m0 + row) * 1024 + k0 + cc * 8,
                           &As[row * 64 + swc * 8]);
            }
        }
        if constexpr (W_BF) {
            const ushort* W = (const ushort*)Wp;
            #pragma unroll
            for (int t = 0; t < 4; ++t) {
                int chunk = t * 4 + wid;
                int row   = chunk * 8 + (lane >> 3);
                int kc    = ((lane & 7) ^ (lane >> 3)) * 8;
                gl_lds16(W + (size_t)(n0 + row) * 1024 + k0 + kc, Bs + chunk * 512);
            }
        } else {
            const float* W = (const float*)Wp;
            #pragma unroll
            for (int i = 0; i < 4; ++i) {
                int cidx = i * 256 + tid;
                int row  = cidx >> 3;
                int cc   = cidx & 7;
                int swc  = cc ^ (row & 7);
                stage8f_sw(W + (size_t)(n0 + row) * 1024 + k0 + cc * 8,
                           &Bs[row * 64 + swc * 8]);
            }
        }
        __syncthreads();

        #pragma unroll
        for (int kk = 0; kk < 2; ++kk) {
            short8 af[4], bfr[4];
            #pragma unroll
            for (int i = 0; i < 4; ++i)
                af[i] = *(const short8*)&As[(wr * 64 + i * 16 + l15) * 64 +
                                            ((kk * 4 + quad) ^ sw) * 8];
            #pragma unroll
            for (int j = 0; j < 4; ++j)
                bfr[j] = *(const short8*)&Bs[(wc * 64 + j * 16 + l15) * 64 +
                                             ((kk * 4 + quad) ^ sw) * 8];
            #pragma unroll
            for (int i = 0; i < 4; ++i)
                #pragma unroll
                for (int j = 0; j < 4; ++j) {
                    if constexpr (MODE == 1)
                        acc[i][j] = __builtin_amdgcn_mfma_f32_16x16x32_bf16(af[i], bfr[j], acc[i][j], 0, 0, 0);
                    else   // C^T: feature-major
                        acc[j][i] = __builtin_amdgcn_mfma_f32_16x16x32_bf16(bfr[j], af[i], acc[j][i], 0, 0, 0);
                }
        }
        __syncthreads();
    }

    if constexpr (MODE == 1) {
        // C layout: row = token (quad*4+r), col = feature (l15) -> tokens contiguous in vt
        ushort* out = (ushort*)outp;
        #pragma unroll
        for (int j = 0; j < 4; ++j) {
            const int col = n0 + wc * 64 + j * 16 + l15;
            const float bv = bias[col];
            const int h = col >> 6;
            const int d = col & 63;
            #pragma unroll
            for (int i = 0; i < 4; ++i) {
                const int rowbase = m0 + wr * 64 + i * 16 + quad * 4;
                int bi = rowbase >> 10, n = rowbase & 1023;
                uint2 w;
                w.x = pkbf2(acc[i][j][0] + bv, acc[i][j][1] + bv);
                w.y = pkbf2(acc[i][j][2] + bv, acc[i][j][3] + bv);
                *(uint2*)&out[(((size_t)(bi * HH + h) * DH + d) * NN) + n] = w;
            }
        }
    } else {
        // C^T layout: row = feature (quad*4+r), col = token (l15) -> features contiguous
        #pragma unroll
        for (int p = 0; p < 4; ++p) {
            const int fb = n0 + wc * 64 + p * 16 + quad * 4;
            const float4v bv4 = *(const float4v*)&bias[fb];
            const int h = fb >> 6;
            const int d = fb & 63;
            #pragma unroll
            for (int q = 0; q < 4; ++q) {
                const int tok = m0 + wr * 64 + q * 16 + l15;
                if constexpr (MODE == 0) {
                    ushort* out = (ushort*)outp;
                    int bi = tok >> 10, n = tok & 1023;
                    uint2 w;
                    w.x = pkbf2((acc[p][q][0] + bv4[0]) * oscale,
                                (acc[p][q][1] + bv4[1]) * oscale);
                    w.y = pkbf2((acc[p][q][2] + bv4[2]) * oscale,
                                (acc[p][q][3] + bv4[3]) * oscale);
                    *(uint2*)&out[(((size_t)(bi * HH + h) * NN + n) * DH) + d] = w;
                } else {
                    float* out = (float*)outp;
                    float4v ov;
                    #pragma unroll
                    for (int r = 0; r < 4; ++r) ov[r] = acc[p][q][r] + bv4[r];
                    *(float4v*)&out[(size_t)tok * 1024 + fb] = ov;
                }
            }
        }
    }
}

template <typename TA, typename TW>
__global__ __launch_bounds__(256) void proj3(const void* q, const void* k, const void* r,
                                             const void* Wq, const void* Wk, const void* Wv,
                                             const float* bq, const float* bk, const float* bv,
                                             ushort* qh, ushort* kh, ushort* vt) {
    __shared__ ushort As[128 * 64];
    __shared__ ushort Bs[128 * 64];
    if (blockIdx.z == 0)      gemm_core<TA, TW, 0>(q, Wq, bq, qh, SCL_Q, As, Bs);
    else if (blockIdx.z == 1) gemm_core<TA, TW, 0>(k, Wk, bk, kh, 1.0f, As, Bs);
    else                      gemm_core<TA, TW, 1>(r, Wv, bv, vt, 1.0f, As, Bs);
}

template <typename TA, typename TW>
__global__ __launch_bounds__(256) void gemm_out(const void* A, const void* W,
                                                const float* bias, float* out) {
    __shared__ ushort As[128 * 64];
    __shared__ ushort Bs[128 * 64];
    gemm_core<TA, TW, 2>(A, W, bias, out, 1.0f, As, Bs);
}

// =====================================================================
// Fused flash attention, max-free softmax, transposed dataflow.
// qh is pre-scaled by log2(e)/8 in proj3 -> p = exp2(sacc) directly.
//   S^T = mfma(K, Q)  -> C/D holds (key=quad*4+r, qrow=l15)
//   P^T write: perm-packed b64 -> P[qrow][key] (stride 72)
//   O^T = mfma(V^T, P^T) -> C/D (d=quad*4+r, qrow=l15) -> b64 global stores
// One block = one (b,h) x 128 Q rows; 4 waves x 32 rows (2 sub-tiles u).
// Grid (bh, qt): all qt blocks of a (b,h) land on one XCD.
// =====================================================================
__global__ __launch_bounds__(256) void attn_fused(const ushort* __restrict__ qh,
                                                  const ushort* __restrict__ kh,
                                                  const ushort* __restrict__ vt,
                                                  ushort* __restrict__ o) {
    __shared__ ushort Ks[64 * 64];       // [key][d] swizzled
    __shared__ ushort Vs[64 * 64];       // [d][key] swizzled
    __shared__ ushort Ps[4][2][16 * 72]; // per-(wave,u) P[qrow][key], stride 72

    const int tid  = threadIdx.x;
    const int wid  = tid >> 6;
    const int lane = tid & 63;
    const int quad = lane >> 4;
    const int l15  = lane & 15;
    const int sw   = l15 & 7;
    const int bh   = blockIdx.x;         // b*16 + h
    const int qt   = blockIdx.y;         // 0..7, 128 Q rows each
    const int h    = bh & 15;
    const int b    = bh >> 4;

    const ushort* qb = qh + (size_t)bh * NN * DH;
    const ushort* kb = kh + (size_t)bh * NN * DH;
    const ushort* vb = vt + (size_t)bh * DH * NN;

    // Q fragments: lane holds Q[qrow][k = s*32 + quad*8 + j]
    short8 qf[2][2];
    #pragma unroll
    for (int u = 0; u < 2; ++u) {
        const int qrow = qt * 128 + wid * 32 + u * 16 + l15;
        qf[u][0] = *(const short8*)(qb + (size_t)qrow * DH + quad * 8);
        qf[u][1] = *(const short8*)(qb + (size_t)qrow * DH + 32 + quad * 8);
    }

    float lsum[2] = {0.f, 0.f};
    float4v oaccT[2][4] = {};

    for (int kt = 0; kt < 16; ++kt) {
        // stage K [64 keys][64 d], V^T [64 d][64 keys], XOR-swizzled
        #pragma unroll
        for (int t = 0; t < 2; ++t) {
            int chunk = t * 4 + wid;
            int row   = chunk * 8 + (lane >> 3);
            int kc    = ((lane & 7) ^ (lane >> 3)) * 8;
            gl_lds16(kb + (size_t)(kt * 64 + row) * DH + kc, Ks + chunk * 512);
            gl_lds16(vb + (size_t)row * NN + kt * 64 + kc, Vs + chunk * 512);
        }
        __syncthreads();

        // S^T = K . Q^T  (keys as rows)
        float4v sacc[2][4] = {};
        #pragma unroll
        for (int s = 0; s < 2; ++s)
            #pragma unroll
            for (int c = 0; c < 4; ++c) {
                short8 kf = *(const short8*)&Ks[(c * 16 + l15) * 64 + ((s * 4 + quad) ^ sw) * 8];
                #pragma unroll
                for (int u = 0; u < 2; ++u)
                    sacc[u][c] = __builtin_amdgcn_mfma_f32_16x16x32_bf16(kf, qf[u][s], sacc[u][c], 0, 0, 0);
            }

        // p = exp2(s) (scale pre-folded into Q); packed b64 P-writes
        #pragma unroll
        for (int u = 0; u < 2; ++u)
            #pragma unroll
            for (int c = 0; c < 4; ++c) {
                float p0 = exp2f(sacc[u][c][0]);
                float p1 = exp2f(sacc[u][c][1]);
                float p2 = exp2f(sacc[u][c][2]);
                float p3 = exp2f(sacc[u][c][3]);
                lsum[u] += (p0 + p1) + (p2 + p3);
                uint2 w;
                w.x = pkbf2(p0, p1);
                w.y = pkbf2(p2, p3);
                *(uint2*)&Ps[wid][u][l15 * 72 + c * 16 + quad * 4] = w;
            }

        // O^T += V^T . P^T   (wave-private Ps: waitcnt only, no barrier)
        #pragma unroll
        for (int s = 0; s < 2; ++s) {
            short8 pf[2];
            #pragma unroll
            for (int u = 0; u < 2; ++u)
                pf[u] = *(const short8*)&Ps[wid][u][l15 * 72 + s * 32 + quad * 8];
            #pragma unroll
            for (int nn = 0; nn < 4; ++nn) {
                short8 vf = *(const short8*)&Vs[(nn * 16 + l15) * 64 + ((s * 4 + quad) ^ sw) * 8];
                #pragma unroll
                for (int u = 0; u < 2; ++u)
                    oaccT[u][nn] = __builtin_amdgcn_mfma_f32_16x16x32_bf16(vf, pf[u], oaccT[u][nn], 0, 0, 0);
            }
        }
        __syncthreads();   // before restaging Ks/Vs
    }

    // epilogue: lane's qrow = l15; reduce denominator over the 4 quads
    #pragma unroll
    for (int u = 0; u < 2; ++u) {
        float t = lsum[u];
        t += __shfl_xor(t, 16);
        t += __shfl_xor(t, 32);
        float inv = 1.0f / t;
        int row = qt * 128 + wid * 32 + u * 16 + l15;
        size_t base = ((size_t)b * NN + row) * DD + h * 64 + quad * 4;
        #pragma unroll
        for (int nn = 0; nn < 4; ++nn) {
            uint2 w;
            w.x = pkbf2(oaccT[u][nn][0] * inv, oaccT[u][nn][1] * inv);
            w.y = pkbf2(oaccT[u][nn][2] * inv, oaccT[u][nn][3] * inv);
            *(uint2*)&o[base + nn * 16] = w;
        }
    }
}

// =====================================================================
// Fused epilogue: res = LN(mha + q; g1,b1); out = LN(relu(res)+res; g2,b2)
// Wave-per-row: 4 rows/block, shuffle-only reductions, no LDS/barriers.
// =====================================================================
__global__ __launch_bounds__(256) void ln_fuse(const float* __restrict__ mha,
                                               const float* __restrict__ q,
                                               const float* __restrict__ g1,
                                               const float* __restrict__ b1,
                                               const float* __restrict__ g2,
                                               const float* __restrict__ b2,
                                               float* __restrict__ out) {
    const int row  = blockIdx.x * 4 + (threadIdx.x >> 6);
    const int lane = threadIdx.x & 63;
    const float* mrow = mha + (size_t)row * 1024;
    const float* qrow = q + (size_t)row * 1024;

    float x[16];
    float s = 0.f, ss = 0.f;
    #pragma unroll
    for (int c = 0; c < 4; ++c) {
        float4v mv = *(const float4v*)(mrow + c * 256 + lane * 4);
        float4v qv = *(const float4v*)(qrow + c * 256 + lane * 4);
        #pragma unroll
        for (int i = 0; i < 4; ++i) {
            float v = mv[i] + qv[i];
            x[c * 4 + i] = v;
            s += v; ss += v * v;
        }
    }
    #pragma unroll
    for (int off = 1; off < 64; off <<= 1) {
        s += __shfl_xor(s, off); ss += __shfl_xor(ss, off);
    }
    float mu = s * (1.0f / 1024.0f);
    float rstd = rsqrtf(ss * (1.0f / 1024.0f) - mu * mu + 1e-5f);

    float y[16];
    float s2 = 0.f, ss2 = 0.f;
    #pragma unroll
    for (int c = 0; c < 4; ++c) {
        float4v g1v = *(const float4v*)(g1 + c * 256 + lane * 4);
        float4v b1v = *(const float4v*)(b1 + c * 256 + lane * 4);
        #pragma unroll
        for (int i = 0; i < 4; ++i) {
            float rr = (x[c * 4 + i] - mu) * rstd * g1v[i] + b1v[i];
            float v = fmaxf(rr, 0.f) + rr;
            y[c * 4 + i] = v;
            s2 += v; ss2 += v * v;
        }
    }
    #pragma unroll
    for (int off = 1; off < 64; off <<= 1) {
        s2 += __shfl_xor(s2, off); ss2 += __shfl_xor(ss2, off);
    }
    float mu2 = s2 * (1.0f / 1024.0f);
    float rstd2 = rsqrtf(ss2 * (1.0f / 1024.0f) - mu2 * mu2 + 1e-5f);

    float* orow = out + (size_t)row * 1024;
    #pragma unroll
    for (int c = 0; c < 4; ++c) {
        float4v g2v = *(const float4v*)(g2 + c * 256 + lane * 4);
        float4v b2v = *(const float4v*)(b2 + c * 256 + lane * 4);
        float4v ov;
        #pragma unroll
        for (int i = 0; i < 4; ++i)
            ov[i] = (y[c * 4 + i] - mu2) * rstd2 * g2v[i] + b2v[i];
        *(float4v*)(orow + c * 256 + lane * 4) = ov;
    }
}

extern "C" void kernel_launch(void* const* d_in, const int* in_sizes, int n_in,
                              void* d_out, int out_size, void* d_ws, size_t ws_size,
                              hipStream_t stream) {
    const float* k  = (const float*)d_in[0];
    const float* q  = (const float*)d_in[1];
    const float* r  = (const float*)d_in[2];
    const float* Wk = (const float*)d_in[3];
    const float* bk = (const float*)d_in[4];
    const float* Wq = (const float*)d_in[5];
    const float* bq = (const float*)d_in[6];
    const float* Wv = (const float*)d_in[7];
    const float* bv = (const float*)d_in[8];
    const float* Wo = (const float*)d_in[9];
    const float* bo = (const float*)d_in[10];
    const float* g1 = (const float*)d_in[11];
    const float* b1 = (const float*)d_in[12];
    const float* g2 = (const float*)d_in[13];
    const float* b2 = (const float*)d_in[14];

    char* ws = (char*)d_ws;
    const size_t MB = 1u << 20;
    dim3 blk(256);

    if (ws_size >= 121 * MB) {
        // full path: pre-convert activations + weights, all-bf16 async GEMMs
        ushort* qc  = (ushort*)(ws);            // 16 MB (dead after proj3)
        ushort* kc  = (ushort*)(ws + 16 * MB);
        ushort* rc  = (ushort*)(ws + 32 * MB);
        ushort* Wqc = (ushort*)(ws + 48 * MB);  // 2 MB each
        ushort* Wkc = (ushort*)(ws + 50 * MB);
        ushort* Wvc = (ushort*)(ws + 52 * MB);
        ushort* Woc = (ushort*)(ws + 54 * MB);
        ushort* qh  = (ushort*)(ws + 56 * MB);  // [B,H,N,DH] (scaled by SCL_Q)
        ushort* kh  = (ushort*)(ws + 72 * MB);
        ushort* vt  = (ushort*)(ws + 88 * MB);  // [B,H,DH,N]
        ushort* ob  = (ushort*)(ws + 104 * MB); // [B,N,D]
        float*  mh  = (float*)(ws);             // 32 MB, reuses qc/kc

        CvtArgs ca;
        ca.src[0] = q;  ca.dst[0] = qc;  ca.n[0] = MTOK * DD;
        ca.src[1] = k;  ca.dst[1] = kc;  ca.n[1] = MTOK * DD;
        ca.src[2] = r;  ca.dst[2] = rc;  ca.n[2] = MTOK * DD;
        ca.src[3] = Wq; ca.dst[3] = Wqc; ca.n[3] = DD * DD;
        ca.src[4] = Wk; ca.dst[4] = Wkc; ca.n[4] = DD * DD;
        ca.src[5] = Wv; ca.dst[5] = Wvc; ca.n[5] = DD * DD;
        ca.src[6] = Wo; ca.dst[6] = Woc; ca.n[6] = DD * DD;
        cvt_bf16<<<dim3(4096, 7), blk, 0, stream>>>(ca);

        proj3<ushort, ushort><<<dim3(64, 8, 3), blk, 0, stream>>>(
            qc, kc, rc, Wqc, Wkc, Wvc, bq, bk, bv, qh, kh, vt);
        attn_fused<<<dim3(HH * BB, 8), blk, 0, stream>>>(qh, kh, vt, ob);
        gemm_out<ushort, ushort><<<dim3(64, 8), blk, 0, stream>>>(ob, Woc, bo, mh);
        ln_fuse<<<dim3(MTOK / 4), blk, 0, stream>>>(mh, q, g1, b1, g2, b2, (float*)d_out);
    } else {
        // 64 MB fallback: f32 A staged in-GEMM; W converts in ob region
        ushort* qh  = (ushort*)(ws);
        ushort* kh  = (ushort*)(ws + 16 * MB);
        ushort* vt  = (ushort*)(ws + 32 * MB);
        ushort* ob  = (ushort*)(ws + 48 * MB);
        ushort* Wqc = (ushort*)(ws + 48 * MB);  // dead once attn writes ob
        ushort* Wkc = (ushort*)(ws + 50 * MB);
        ushort* Wvc = (ushort*)(ws + 52 * MB);
        float*  mh  = (float*)(ws);             // reuses qh/kh after attn

        CvtArgs ca;
        ca.src[0] = Wq; ca.dst[0] = Wqc; ca.n[0] = DD * DD;
        ca.src[1] = Wk; ca.dst[1] = Wkc; ca.n[1] = DD * DD;
        ca.src[2] = Wv; ca.dst[2] = Wvc; ca.n[2] = DD * DD;
        for (int i = 3; i < 7; ++i) { ca.src[i] = Wq; ca.dst[i] = Wqc; ca.n[i] = 0; }
        cvt_bf16<<<dim3(512, 3), blk, 0, stream>>>(ca);

        proj3<float, ushort><<<dim3(64, 8, 3), blk, 0, stream>>>(
            q, k, r, Wqc, Wkc, Wvc, bq, bk, bv, qh, kh, vt);
        attn_fused<<<dim3(HH * BB, 8), blk, 0, stream>>>(qh, kh, vt, ob);
        gemm_out<ushort, float><<<dim3(64, 8), blk, 0, stream>>>(ob, Wo, bo, mh);
        ln_fuse<<<dim3(MTOK / 4), blk, 0, stream>>>(mh, q, g1, b1, g2, b2, (float*)d_out);
    }
}